// Round 1
// baseline (873.778 us; speedup 1.0000x reference)
//
#include <hip/hip_runtime.h>
#include <cmath>

// MZILinear: out = x @ W^T, W = diag(dU)*Ru*diag(sigma*dV)*Rv,
// Ru/Rv = product of 130816 Givens rotations (Reck order) applied to I.
//
// Pipeline:
//  1) trig_kernel  : (c,s) pairs for both phi arrays
//  2) group_kernel : split rotation sequence into G contiguous blocks, build
//                    each block product from identity (per-column LDS chains;
//                    pivot-row value lives in a register across its inner loop)
//  3) combine_kernel (log2 G rounds): tree-multiply block products
//                    (identity-block copy fast paths + K-truncation)
//  4) wasm_kernel  : W = diag(dU) * Ru * diag(sigma*dV) * Rv  (one 512^3 matmul)
//  5) gemm_kernel  : out[32768,512] = x * W^T (fp32 VALU, 128x64 tile)

#define NDIM 512
#define NPAIR 130816            // 512*511/2
#define MAT (NDIM * NDIM)       // 262144 floats per matrix slot

// T(i) = number of rotations before pivot i starts = i*(1023-i)/2
__device__ __forceinline__ int T_of(int i) { return (i * (1023 - i)) >> 1; }

// largest i with T(i) <= k
__device__ __forceinline__ int pivot_of(int k) {
    int lo = 0, hi = 511;
    while (lo < hi) {
        int mid = (lo + hi + 1) >> 1;
        if (T_of(mid) <= k) lo = mid; else hi = mid - 1;
    }
    return lo;
}

// ---------------------------------------------------------------- trig
__global__ __launch_bounds__(256) void trig_kernel(const float* __restrict__ pU,
                                                   const float* __restrict__ pV,
                                                   float2* __restrict__ csU,
                                                   float2* __restrict__ csV) {
    int idx = blockIdx.x * 256 + threadIdx.x;
    if (idx < NPAIR) {
        float s, c;
        sincosf(pU[idx], &s, &c);
        csU[idx] = make_float2(c, s);
    } else if (idx < 2 * NPAIR) {
        int m = idx - NPAIR;
        float s, c;
        sincosf(pV[m], &s, &c);
        csV[m] = make_float2(c, s);
    }
}

// ---------------------------------------------------------------- group products
// One wave per block; 32 columns per block (lanes 32..63 idle -> 64KB static LDS,
// no dynamic-LDS risk; serial chain is issue-bound per wave so same wall time).
// Applies rotations k in [g*R, (g+1)*R) to identity, writes full 512x512 slot.
__global__ __launch_bounds__(64) void group_kernel(const float2* __restrict__ csU,
                                                   const float2* __restrict__ csV,
                                                   float* __restrict__ bufA,
                                                   int R, int capA) {
    __shared__ float v[NDIM * 32];
    const int lane = threadIdx.x;
    if (lane >= 32) return;                    // half-wave active; no barriers used
    const int col0 = blockIdx.x * 32;
    const int col  = col0 + lane;
    const int g    = blockIdx.y;
    const int side = blockIdx.z;               // 0 = U, 1 = V
    const int k0 = g * R, k1 = k0 + R;
    const int i0 = pivot_of(k0);
    float* out = bufA + ((size_t)(side * capA + g)) * MAT;

    if (col0 + 32 <= i0) {                     // columns < first pivot: identity
        for (int r = 0; r < NDIM; ++r)
            out[(size_t)r * NDIM + col] = (r == col) ? 1.f : 0.f;
        return;
    }
    const float2* __restrict__ csp = side ? csV : csU;

    for (int r = 0; r < NDIM; ++r)             // column state = e_col
        v[r * 32 + lane] = (r == col) ? 1.f : 0.f;

    int i = i0;
    int j = 511 - (k0 - T_of(i0));
    int k = k0;
    while (k < k1 && i < 511) {
        float vi = v[i * 32 + lane];           // pivot-row value cached in register
        int cnt = min(k1 - k, j - i);          // rotations left in this pivot/group
        #pragma unroll 4
        for (int t = 0; t < cnt; ++t) {
            float2 cs = csp[k + t];            // wave-uniform -> scalar loads
            float vj  = v[(j - t) * 32 + lane];
            float vjn = fmaf(cs.y, vi, cs.x * vj);   // row q = s*rp + c*rq
            vi        = fmaf(cs.x, vi, -(cs.y * vj));// row p = c*rp - s*rq
            v[(j - t) * 32 + lane] = vjn;
        }
        k += cnt; j -= cnt;
        v[i * 32 + lane] = vi;
        if (j == i) { ++i; j = 511; }
    }
    for (int r = 0; r < NDIM; ++r)
        out[(size_t)r * NDIM + col] = v[r * 32 + lane];
}

// ---------------------------------------------------------------- combine rounds
// C[m] = src[2m+1] * src[2m]  (X = later rotation block = left operand).
// X is identity on rows < ax; Y is identity on cols < ay.
__global__ __launch_bounds__(256) void combine_kernel(const float* __restrict__ src,
                                                      float* __restrict__ dst,
                                                      int srcCap, int dstCap,
                                                      int half, int R, int P) {
    const int side = blockIdx.z / P, m = blockIdx.z % P;
    const int bx = blockIdx.x & 7, by = blockIdx.x >> 3;
    const int row0 = by * 64, col0 = bx * 64;
    const float* __restrict__ X = src + ((size_t)(side * srcCap + 2 * m + 1)) * MAT;
    const float* __restrict__ Y = src + ((size_t)(side * srcCap + 2 * m)) * MAT;
    float* __restrict__ C = dst + ((size_t)(side * dstCap + m)) * MAT;
    const int ax = pivot_of((2 * m * half + half) * R);
    const int ay = pivot_of((2 * m * half) * R);
    const int tid = threadIdx.x;

    if (row0 + 64 <= ax) {                     // X rows identity -> C tile = Y tile
        for (int t = tid; t < 64 * 16; t += 256) {
            int r = t >> 4, q = (t & 15) * 4;
            size_t off = (size_t)(row0 + r) * NDIM + col0 + q;
            *(float4*)&C[off] = *(const float4*)&Y[off];
        }
        return;
    }
    if (col0 + 64 <= ay) {                     // Y cols identity -> C tile = X tile
        for (int t = tid; t < 64 * 16; t += 256) {
            int r = t >> 4, q = (t & 15) * 4;
            size_t off = (size_t)(row0 + r) * NDIM + col0 + q;
            *(float4*)&C[off] = *(const float4*)&X[off];
        }
        return;
    }

    __shared__ float Xs[64][36];
    __shared__ float Ys[32][68];
    const int tx = tid & 15, ty = tid >> 4;
    float acc[4][4] = {};
    // rows >= ax have X[r,k<ax] == 0 -> start K loop at ax (rounded down to 32)
    const int kt0 = (row0 >= ax) ? (ax >> 5) : 0;
    for (int kt = kt0; kt < 16; ++kt) {
        {
            int r = tid >> 2, q = (tid & 3) * 4;
            const float* xr = X + (size_t)(row0 + r) * NDIM + kt * 32;
            *(float4*)&Xs[r][q]      = *(const float4*)(xr + q);
            *(float4*)&Xs[r][q + 16] = *(const float4*)(xr + q + 16);
        }
        {
            int kk = tid >> 4, cq = (tid & 15) * 4;
            *(float4*)&Ys[kk][cq]      = *(const float4*)(Y + (size_t)(kt * 32 + kk) * NDIM + col0 + cq);
            *(float4*)&Ys[kk + 16][cq] = *(const float4*)(Y + (size_t)(kt * 32 + kk + 16) * NDIM + col0 + cq);
        }
        __syncthreads();
        #pragma unroll
        for (int kk = 0; kk < 32; ++kk) {
            float av[4] = {Xs[ty * 4 + 0][kk], Xs[ty * 4 + 1][kk],
                           Xs[ty * 4 + 2][kk], Xs[ty * 4 + 3][kk]};
            float4 B = *(const float4*)&Ys[kk][tx * 4];
            float bv[4] = {B.x, B.y, B.z, B.w};
            #pragma unroll
            for (int mm = 0; mm < 4; ++mm)
                #pragma unroll
                for (int nn = 0; nn < 4; ++nn)
                    acc[mm][nn] = fmaf(av[mm], bv[nn], acc[mm][nn]);
        }
        __syncthreads();
    }
    #pragma unroll
    for (int mm = 0; mm < 4; ++mm) {
        float4 st = make_float4(acc[mm][0], acc[mm][1], acc[mm][2], acc[mm][3]);
        *(float4*)&C[(size_t)(row0 + ty * 4 + mm) * NDIM + col0 + tx * 4] = st;
    }
}

// ---------------------------------------------------------------- W assembly
// W = diag(dU) * Ru * diag(sigma*dV) * Rv
__global__ __launch_bounds__(256) void wasm_kernel(const float* __restrict__ Ru,
                                                   const float* __restrict__ Rv,
                                                   const float* __restrict__ dU,
                                                   const float* __restrict__ dV,
                                                   const float* __restrict__ sg,
                                                   float* __restrict__ W) {
    const int bx = blockIdx.x & 7, by = blockIdx.x >> 3;
    const int row0 = by * 64, col0 = bx * 64;
    __shared__ float Xs[64][36];
    __shared__ float Ys[32][68];
    const int tid = threadIdx.x;
    const int tx = tid & 15, ty = tid >> 4;
    float acc[4][4] = {};
    for (int kt = 0; kt < 16; ++kt) {
        {
            int r = tid >> 2, q = (tid & 3) * 4;
            const float* xr = Ru + (size_t)(row0 + r) * NDIM + kt * 32;
            *(float4*)&Xs[r][q]      = *(const float4*)(xr + q);
            *(float4*)&Xs[r][q + 16] = *(const float4*)(xr + q + 16);
        }
        {
            int kk = tid >> 4, cq = (tid & 15) * 4;
            int kg = kt * 32 + kk;
            float sd = sg[kg] * dV[kg];
            float4 b = *(const float4*)(Rv + (size_t)kg * NDIM + col0 + cq);
            b.x *= sd; b.y *= sd; b.z *= sd; b.w *= sd;
            *(float4*)&Ys[kk][cq] = b;
            int kg2 = kg + 16;
            float sd2 = sg[kg2] * dV[kg2];
            float4 b2 = *(const float4*)(Rv + (size_t)kg2 * NDIM + col0 + cq);
            b2.x *= sd2; b2.y *= sd2; b2.z *= sd2; b2.w *= sd2;
            *(float4*)&Ys[kk + 16][cq] = b2;
        }
        __syncthreads();
        #pragma unroll
        for (int kk = 0; kk < 32; ++kk) {
            float av[4] = {Xs[ty * 4 + 0][kk], Xs[ty * 4 + 1][kk],
                           Xs[ty * 4 + 2][kk], Xs[ty * 4 + 3][kk]};
            float4 B = *(const float4*)&Ys[kk][tx * 4];
            float bv[4] = {B.x, B.y, B.z, B.w};
            #pragma unroll
            for (int mm = 0; mm < 4; ++mm)
                #pragma unroll
                for (int nn = 0; nn < 4; ++nn)
                    acc[mm][nn] = fmaf(av[mm], bv[nn], acc[mm][nn]);
        }
        __syncthreads();
    }
    #pragma unroll
    for (int mm = 0; mm < 4; ++mm) {
        float du = dU[row0 + ty * 4 + mm];
        float4 st = make_float4(acc[mm][0] * du, acc[mm][1] * du,
                                acc[mm][2] * du, acc[mm][3] * du);
        *(float4*)&W[(size_t)(row0 + ty * 4 + mm) * NDIM + col0 + tx * 4] = st;
    }
}

// ---------------------------------------------------------------- final GEMM
// out[t,o] = sum_i x[t,i] * W[o,i].  128x64 tile, BK=32, 8x4 micro-tile.
// Both operands staged K-major-transposed into LDS so fragment reads are b128.
__global__ __launch_bounds__(256) void gemm_kernel(const float* __restrict__ x,
                                                   const float* __restrict__ W,
                                                   float* __restrict__ out) {
    const int col0 = blockIdx.x * 64;
    const int row0 = blockIdx.y * 128;
    __shared__ float Xs[32][132];   // [k][token]
    __shared__ float Ys[32][68];    // [k][outcol]
    const int tid = threadIdx.x;
    const int tx = tid & 15, ty = tid >> 4;
    float acc[8][4] = {};
    for (int kt = 0; kt < 16; ++kt) {
        {
            int r = tid & 127;
            int ks = (tid >> 7) * 16;
            const float* xr = x + (size_t)(row0 + r) * NDIM + kt * 32 + ks;
            #pragma unroll
            for (int u = 0; u < 4; ++u) {
                float4 vv = *(const float4*)(xr + u * 4);
                Xs[ks + u * 4 + 0][r] = vv.x;
                Xs[ks + u * 4 + 1][r] = vv.y;
                Xs[ks + u * 4 + 2][r] = vv.z;
                Xs[ks + u * 4 + 3][r] = vv.w;
            }
        }
        {
            int o = tid & 63;
            int ks = (tid >> 6) * 4;
            const float* wr = W + (size_t)(col0 + o) * NDIM + kt * 32;
            float4 w0 = *(const float4*)(wr + ks);
            float4 w1 = *(const float4*)(wr + ks + 16);
            Ys[ks + 0][o] = w0.x; Ys[ks + 1][o] = w0.y;
            Ys[ks + 2][o] = w0.z; Ys[ks + 3][o] = w0.w;
            Ys[ks + 16][o] = w1.x; Ys[ks + 17][o] = w1.y;
            Ys[ks + 18][o] = w1.z; Ys[ks + 19][o] = w1.w;
        }
        __syncthreads();
        #pragma unroll
        for (int kk = 0; kk < 32; ++kk) {
            float4 A0 = *(const float4*)&Xs[kk][ty * 8];
            float4 A1 = *(const float4*)&Xs[kk][ty * 8 + 4];
            float4 B  = *(const float4*)&Ys[kk][tx * 4];
            float av[8] = {A0.x, A0.y, A0.z, A0.w, A1.x, A1.y, A1.z, A1.w};
            float bv[4] = {B.x, B.y, B.z, B.w};
            #pragma unroll
            for (int mm = 0; mm < 8; ++mm)
                #pragma unroll
                for (int nn = 0; nn < 4; ++nn)
                    acc[mm][nn] = fmaf(av[mm], bv[nn], acc[mm][nn]);
        }
        __syncthreads();
    }
    #pragma unroll
    for (int mm = 0; mm < 8; ++mm) {
        float4 st = make_float4(acc[mm][0], acc[mm][1], acc[mm][2], acc[mm][3]);
        *(float4*)&out[(size_t)(row0 + ty * 8 + mm) * NDIM + col0 + tx * 4] = st;
    }
}

// ---------------------------------------------------------------- host
extern "C" void kernel_launch(void* const* d_in, const int* in_sizes, int n_in,
                              void* d_out, int out_size, void* d_ws, size_t ws_size,
                              hipStream_t stream) {
    (void)in_sizes; (void)n_in; (void)out_size;
    const float* xp   = (const float*)d_in[0];
    const float* phiU = (const float*)d_in[1];
    const float* dUp  = (const float*)d_in[2];
    const float* phiV = (const float*)d_in[3];
    const float* dVp  = (const float*)d_in[4];
    const float* sgp  = (const float*)d_in[5];
    float* out = (float*)d_out;
    float* wsf = (float*)d_ws;

    // Pick largest G (rotation blocks per matrix) that fits the workspace.
    // floats needed: cs (4*NPAIR) + bufA (2*G*MAT) + bufB (G*MAT if G>1) + W (MAT)
    int G = 16;
    while (G > 1) {
        size_t needFloats = (size_t)4 * NPAIR + (size_t)2 * G * MAT
                          + (size_t)G * MAT + MAT;
        if (needFloats * 4 <= ws_size) break;
        G >>= 1;
    }
    const int R = NPAIR / G;   // exact for G in {1,2,4,8,16}

    float2* csU = (float2*)wsf;
    float2* csV = csU + NPAIR;
    float* bufA = wsf + (size_t)4 * NPAIR;
    float* bufB = bufA + (size_t)2 * G * MAT;
    const int capB = (G > 1) ? G / 2 : 1;
    float* Wbuf = (G > 1) ? (bufB + (size_t)2 * capB * MAT) : bufB;

    // 1) trig
    trig_kernel<<<dim3((2 * NPAIR + 255) / 256), 256, 0, stream>>>(phiU, phiV, csU, csV);

    // 2) block products (both sides in one launch)
    group_kernel<<<dim3(16, G, 2), 64, 0, stream>>>(csU, csV, bufA, R, G);

    // 3) tree combine: log2(G) rounds, ping-pong bufA <-> bufB
    const float* cur = bufA;
    float* oth = bufB;
    int curCap = G, othCap = capB;
    for (int P = G / 2, half = 1; P >= 1; P >>= 1, half <<= 1) {
        combine_kernel<<<dim3(64, 1, 2 * P), 256, 0, stream>>>(cur, oth, curCap, othCap, half, R, P);
        const float* t = cur; cur = oth; oth = (float*)t;
        int tc = curCap; curCap = othCap; othCap = tc;
    }
    const float* Ru = cur;
    const float* Rv = cur + (size_t)curCap * MAT;

    // 4) W assembly
    wasm_kernel<<<dim3(64), 256, 0, stream>>>(Ru, Rv, dUp, dVp, sgp, Wbuf);

    // 5) out = x * W^T
    gemm_kernel<<<dim3(8, 256), 256, 0, stream>>>(xp, Wbuf, out);
}